// Round 1
// baseline (331.469 us; speedup 1.0000x reference)
//
#include <hip/hip_runtime.h>

#ifndef __HIP_DEVICE_COMPILE__
#include <cstdio>
#endif

constexpr int BN   = 131072;   // points
constexpr int HID  = 20;       // hidden width
constexpr int NLAY = 7;        // hidden->hidden layers (N_HID_LAYERS-1)

// LDS layout (floats)
constexpr int OFF_WH   = 0;            // 7*20*20 = 2800
constexpr int OFF_BH   = 2800;         // 7*20    = 140
constexpr int OFF_WIN  = 2940;         // 3*20    = 60
constexpr int OFF_BIN  = 3000;         // 20
constexpr int OFF_WOUT = 3020;         // 20*2    = 40
constexpr int OFF_BOUT = 3060;         // 2
constexpr int LDS_TOT  = 3062;

__device__ __forceinline__ float fast_tanh(float a) {
    // tanh(a) = 1 - 2/(1 + e^{2a});  e^{2a} = exp2(a * 2*log2(e))
    float e = __builtin_amdgcn_exp2f(a * 2.8853900817779268f);
    float r = __builtin_amdgcn_rcpf(e + 1.0f);
    return __builtin_fmaf(-2.0f, r, 1.0f);
}

// Univariate 3rd-order jet through tanh (Faa di Bruno):
// y1 = f' a1 ; y2 = f'' a1^2 + f' a2 ; y3 = f''' a1^3 + 3 f'' a1 a2 + f' a3
__device__ __forceinline__ void tanh_jet(float av, float a1, float a2, float a3,
                                         float& ov, float& o1, float& o2, float& o3) {
    float s  = fast_tanh(av);
    float s1 = 1.0f - s * s;               // f'
    float f2 = -2.0f * s * s1;             // f''
    float f3 = s1 * (4.0f * s * s - 2.0f * s1); // f'''
    ov = s;
    o1 = s1 * a1;
    o2 = s1 * a2 + f2 * a1 * a1;
    o3 = s1 * a3 + 3.0f * f2 * a1 * a2 + f3 * a1 * a1 * a1;
}

__global__ __launch_bounds__(256, 2) void pinn_jets(
    const float* __restrict__ x, const float* __restrict__ y, const float* __restrict__ t,
    const float* __restrict__ Win, const float* __restrict__ bin,
    const float* __restrict__ Wh,  const float* __restrict__ bh,
    const float* __restrict__ Wout,const float* __restrict__ bout,
    float* __restrict__ ws)
{
    __shared__ float smem[LDS_TOT];
    const int tid = threadIdx.x;
    for (int i = tid; i < 2800; i += 256) smem[OFF_WH + i] = Wh[i];
    for (int i = tid; i < 140;  i += 256) smem[OFF_BH + i] = bh[i];
    if (tid < 60) smem[OFF_WIN  + tid] = Win[tid];
    if (tid < 20) smem[OFF_BIN  + tid] = bin[tid];
    if (tid < 40) smem[OFF_WOUT + tid] = Wout[tid];
    if (tid < 2)  smem[OFF_BOUT + tid] = bout[tid];
    __syncthreads();

    const int pt  = blockIdx.x * 256 + tid;
    const int jet = blockIdx.y;

    // jet directions
    const float DXA[7] = {1.f, 0.f, 1.f,  1.f, 1.f, 0.f, 0.f};
    const float DYA[7] = {0.f, 1.f, 1.f, -1.f, 0.f, 1.f, 0.f};
    const float DTA[7] = {0.f, 0.f, 0.f,  0.f, 1.f, 1.f, 1.f};
    const float dx = DXA[jet], dy = DYA[jet], dt = DTA[jet];

    const float xv = x[pt], yv = y[pt], tv = t[pt];

    float hv[HID], h1[HID], h2[HID], h3[HID];

    // ---- input layer: a = z@Win + bin; jet of a: a1 = d@Win, a2=a3=0
    #pragma unroll
    for (int o = 0; o < HID; ++o) {
        float w0 = smem[OFF_WIN + o];
        float w1 = smem[OFF_WIN + HID + o];
        float w2 = smem[OFF_WIN + 2 * HID + o];
        float av = smem[OFF_BIN + o] + xv * w0 + yv * w1 + tv * w2;
        float a1 = dx * w0 + dy * w1 + dt * w2;
        tanh_jet(av, a1, 0.0f, 0.0f, hv[o], h1[o], h2[o], h3[o]);
    }

    // ---- hidden layers
    for (int l = 0; l < NLAY; ++l) {
        float nv[HID], n1[HID], n2[HID], n3[HID];
        const float* Wl = &smem[OFF_WH + l * (HID * HID)];
        const float* bl = &smem[OFF_BH + l * HID];
        #pragma unroll
        for (int ob = 0; ob < 5; ++ob) {
            const int o0 = ob * 4;
            float4 bv = *(const float4*)&bl[o0];
            float accv[4] = {bv.x, bv.y, bv.z, bv.w};
            float acc1[4] = {0.f, 0.f, 0.f, 0.f};
            float acc2[4] = {0.f, 0.f, 0.f, 0.f};
            float acc3[4] = {0.f, 0.f, 0.f, 0.f};
            #pragma unroll
            for (int i = 0; i < HID; ++i) {
                float4 w = *(const float4*)&Wl[i * HID + o0];
                const float wv[4] = {w.x, w.y, w.z, w.w};
                #pragma unroll
                for (int k = 0; k < 4; ++k) {
                    accv[k] += hv[i] * wv[k];
                    acc1[k] += h1[i] * wv[k];
                    acc2[k] += h2[i] * wv[k];
                    acc3[k] += h3[i] * wv[k];
                }
            }
            #pragma unroll
            for (int k = 0; k < 4; ++k)
                tanh_jet(accv[k], acc1[k], acc2[k], acc3[k],
                         nv[o0 + k], n1[o0 + k], n2[o0 + k], n3[o0 + k]);
        }
        #pragma unroll
        for (int o = 0; o < HID; ++o) { hv[o] = nv[o]; h1[o] = n1[o]; h2[o] = n2[o]; h3[o] = n3[o]; }
    }

    // ---- output layer: out[0] = psi, out[1] = p
    float psi1 = 0.f, psi2 = 0.f, psi3 = 0.f;
    float pv = smem[OFF_BOUT + 1], pp1 = 0.f;
    #pragma unroll
    for (int i = 0; i < HID; ++i) {
        float w0 = smem[OFF_WOUT + 2 * i];
        float w1 = smem[OFF_WOUT + 2 * i + 1];
        psi1 += h1[i] * w0;
        psi2 += h2[i] * w0;
        psi3 += h3[i] * w0;
        pv   += hv[i] * w1;
        pp1  += h1[i] * w1;
    }

    // ---- store jet results, field-major for coalescing
    switch (jet) {
        case 0: ws[0*BN+pt]=psi1; ws[1*BN+pt]=psi2; ws[2*BN+pt]=psi3; ws[3*BN+pt]=pv; ws[4*BN+pt]=pp1; break;
        case 1: ws[5*BN+pt]=psi1; ws[6*BN+pt]=psi2; ws[7*BN+pt]=psi3; ws[8*BN+pt]=pp1; break;
        case 2: ws[9*BN+pt]=psi2;  ws[10*BN+pt]=psi3; break;
        case 3: ws[11*BN+pt]=psi2; ws[12*BN+pt]=psi3; break;
        case 4: ws[13*BN+pt]=psi2; break;
        case 5: ws[14*BN+pt]=psi2; break;
        case 6: ws[15*BN+pt]=psi2; break;
    }
}

__global__ __launch_bounds__(256) void pinn_combine(
    const float* __restrict__ ws,
    const float* __restrict__ u, const float* __restrict__ v,
    const float* __restrict__ lam1p, const float* __restrict__ lam2p,
    float* __restrict__ out)
{
    const int tid = threadIdx.x;
    const int pt  = blockIdx.x * 256 + tid;

    const float psi_x   = ws[0*BN+pt];
    const float psi_xx  = ws[1*BN+pt];
    const float psi_xxx = ws[2*BN+pt];
    const float pv      = ws[3*BN+pt];
    const float p_x     = ws[4*BN+pt];
    const float psi_y   = ws[5*BN+pt];
    const float psi_yy  = ws[6*BN+pt];
    const float psi_yyy = ws[7*BN+pt];
    const float p_y     = ws[8*BN+pt];
    const float d2pp    = ws[9*BN+pt];
    const float d3pp    = ws[10*BN+pt];
    const float d2pm    = ws[11*BN+pt];
    const float d3pm    = ws[12*BN+pt];
    const float d2xt    = ws[13*BN+pt];
    const float d2yt    = ws[14*BN+pt];
    const float d2tt    = ws[15*BN+pt];

    const float psi_xy  = 0.5f * (d2pp - psi_xx - psi_yy);
    const float psi_tt  = d2tt;
    const float psi_xt  = 0.5f * (d2xt - psi_xx - psi_tt);
    const float psi_yt  = 0.5f * (d2yt - psi_yy - psi_tt);
    const float psi_xxy = (d3pp - d3pm - 2.0f * psi_yyy) * (1.0f / 6.0f);
    const float psi_xyy = (d3pp + d3pm - 2.0f * psi_xxx) * (1.0f / 6.0f);

    const float u_pred = psi_y;
    const float v_pred = -psi_x;
    const float u_x = psi_xy,  u_y = psi_yy,  u_t = psi_yt;
    const float v_x = -psi_xx, v_y = -psi_xy, v_t = -psi_xt;
    const float u_xx = psi_xxy, u_yy = psi_yyy;
    const float v_xx = -psi_xxx, v_yy = -psi_xyy;

    const float lam1 = lam1p[0];
    const float lam2 = lam2p[0];

    const float f_u = lam1 * (u_t + u_pred * u_x + v_pred * u_y) + p_x - lam2 * (u_xx + u_yy);
    const float f_v = lam1 * (v_t + u_pred * v_x + v_pred * v_y) - lam1 * 9.81f + p_y
                      - lam2 * (v_xx + v_yy);

    out[3*pt+0] = pv;
    out[3*pt+1] = u_pred;
    out[3*pt+2] = v_pred;

    const float du = u[pt] - u_pred;
    const float dv = v[pt] - v_pred;
    float term = du * du + dv * dv + f_u * f_u + f_v * f_v;

    // wave (64) reduce, then block reduce, then one atomic per block
    #pragma unroll
    for (int off = 32; off > 0; off >>= 1) term += __shfl_down(term, off);
    __shared__ float wsum[4];
    const int lane = tid & 63, wid = tid >> 6;
    if (lane == 0) wsum[wid] = term;
    __syncthreads();
    if (tid == 0) atomicAdd(&out[3*BN], wsum[0] + wsum[1] + wsum[2] + wsum[3]);
}

extern "C" void kernel_launch(void* const* d_in, const int* in_sizes, int n_in,
                              void* d_out, int out_size, void* d_ws, size_t ws_size,
                              hipStream_t stream) {
    const float* x    = (const float*)d_in[0];
    const float* y    = (const float*)d_in[1];
    const float* t    = (const float*)d_in[2];
    const float* u    = (const float*)d_in[3];
    const float* v    = (const float*)d_in[4];
    const float* Win  = (const float*)d_in[5];
    const float* bin  = (const float*)d_in[6];
    const float* Wh   = (const float*)d_in[7];
    const float* bh   = (const float*)d_in[8];
    const float* Wout = (const float*)d_in[9];
    const float* bout = (const float*)d_in[10];
    const float* lam1 = (const float*)d_in[11];
    const float* lam2 = (const float*)d_in[12];

    float* out = (float*)d_out;
    float* ws  = (float*)d_ws;

    // zero the loss accumulator (graph-capture-safe async memset)
    hipMemsetAsync(out + 3 * BN, 0, sizeof(float), stream);

    dim3 g1(BN / 256, 7);
    pinn_jets<<<g1, 256, 0, stream>>>(x, y, t, Win, bin, Wh, bh, Wout, bout, ws);
    pinn_combine<<<BN / 256, 256, 0, stream>>>(ws, u, v, lam1, lam2, out);
}